// Round 17
// baseline (160.842 us; speedup 1.0000x reference)
//
#include <hip/hip_runtime.h>
#include <math.h>

#define TT 2048
#define TD 256
#define BN 2048
#define BT 32768
#define KTOP 100
#define CAP 1024     // per-row global candidate list capacity
#define LCAP 1024    // per-block LDS candidate buffer
#define THETA -0.15f // candidate threshold on cos
#define BROWS 128    // rows per block (4 row-groups x 32)
#define SLICE 512    // cols per block
#define NITER 16     // SLICE / 32 (32 cols per iter: 2 col-groups x 16)
#define FSCALE 301.176470588f  // 256 / 0.85 (kfinal bins over [-1, THETA))
#define GH 32        // ghist partial slices

typedef __attribute__((ext_vector_type(4))) float float4v;
typedef __attribute__((ext_vector_type(2))) long long2v;

// pack 4 floats -> 4 fp8 (e4m3, HW cvt; same format the fp8 MFMA consumes)
__device__ __forceinline__ unsigned pk4(float a, float b, float c, float d) {
    int u = __builtin_amdgcn_cvt_pk_fp8_f32(a, b, 0, false);
    u = __builtin_amdgcn_cvt_pk_fp8_f32(c, d, u, true);
    return (unsigned)u;
}

// fp8 fragment-tiled layout, per 16-col/row block (4096 B):
//   [ks2(4)][g(4)][c(16)][16B = ks-even 8B | ks-odd 8B]
// dim d -> ks = d>>5, ks2 = ks>>1, half = ks&1, g = (d>>3)&3, e = d&7
// kpass loads one long2 per (ks2, lane): cblk*256 + ks2*64 + lane.

// ---------------------------------------------------------------------------
// Fused init kernel. Block ranges:
//   [0, 2048)      : kprep — normalize 16 negatives, store fp8 fragment-tiled
//   [2048, 2560)   : kanchor — 4 anchor rows per block (fp8 tiled + fp32 num)
//   [2560, 2592)   : ghist partial slices
//   [2592, 2600)   : zero cnt/flag
// ---------------------------------------------------------------------------
__global__ __launch_bounds__(256) void kinit(const float* __restrict__ ctx,
                                             const float* __restrict__ tgt,
                                             const int* __restrict__ mask_index,
                                             const int* __restrict__ phone,
                                             unsigned char* __restrict__ negT,
                                             unsigned char* __restrict__ ancT,
                                             float* __restrict__ acosP,
                                             int* __restrict__ phoneA,
                                             unsigned* __restrict__ ghp,
                                             int* __restrict__ cnt,
                                             int* __restrict__ flagA) {
    const int bid = blockIdx.x;
    const int tid = threadIdx.x;

    if (bid < 2048) {   // ---- kprep: colblk bid, 16 cols, barrier-free ----
        const int col = tid >> 4;     // 0..15 within colblk
        const int seg = tid & 15;     // dims [seg*16, seg*16+16)
        const float* src = tgt + ((size_t)bid * 16 + col) * TD + seg * 16;
        float4 v0 = *reinterpret_cast<const float4*>(src + 0);
        float4 v1 = *reinterpret_cast<const float4*>(src + 4);
        float4 v2 = *reinterpret_cast<const float4*>(src + 8);
        float4 v3 = *reinterpret_cast<const float4*>(src + 12);
        float s = v0.x * v0.x + v0.y * v0.y + v0.z * v0.z + v0.w * v0.w
                + v1.x * v1.x + v1.y * v1.y + v1.z * v1.z + v1.w * v1.w
                + v2.x * v2.x + v2.y * v2.y + v2.z * v2.z + v2.w * v2.w
                + v3.x * v3.x + v3.y * v3.y + v3.z * v3.z + v3.w * v3.w;
        s += __shfl_xor(s, 1, 64);
        s += __shfl_xor(s, 2, 64);
        s += __shfl_xor(s, 4, 64);
        s += __shfl_xor(s, 8, 64);
        const float iv = 1.0f / sqrtf(s);
        const int ks2 = seg >> 2;
        const int half = (seg >> 1) & 1;
        const int ga = (seg * 2) & 3;
        const int gb = (seg * 2 + 1) & 3;
        unsigned char* base = negT + (size_t)bid * 4096;
        uint2 pa, pb;
        pa.x = pk4(v0.x * iv, v0.y * iv, v0.z * iv, v0.w * iv);
        pa.y = pk4(v1.x * iv, v1.y * iv, v1.z * iv, v1.w * iv);
        pb.x = pk4(v2.x * iv, v2.y * iv, v2.z * iv, v2.w * iv);
        pb.y = pk4(v3.x * iv, v3.y * iv, v3.z * iv, v3.w * iv);
        *reinterpret_cast<uint2*>(base + (((ks2 * 4 + ga) * 16 + col) * 16) + half * 8) = pa;
        *reinterpret_cast<uint2*>(base + (((ks2 * 4 + gb) * 16 + col) * 16) + half * 8) = pb;
        return;
    }
    if (bid < 2560) {   // ---- kanchor: rows (bid-2048)*4 .. +3 ----
        const int r = (bid - 2048) * 4 + (tid >> 6);
        const int lane = tid & 63;
        const int b = r >> 7;
        const int n = r & 127;
        const int t = mask_index[n];
        const size_t base = ((size_t)b * TT + t) * TD;
        float4 a = *reinterpret_cast<const float4*>(ctx + base + lane * 4);
        float4 p = *reinterpret_cast<const float4*>(tgt + base + lane * 4);
        float sa = a.x * a.x + a.y * a.y + a.z * a.z + a.w * a.w;
        float sp = p.x * p.x + p.y * p.y + p.z * p.z + p.w * p.w;
        float dp = a.x * p.x + a.y * p.y + a.z * p.z + a.w * p.w;
        for (int off = 32; off > 0; off >>= 1) {
            sa += __shfl_down(sa, off, 64);
            sp += __shfl_down(sp, off, 64);
            dp += __shfl_down(dp, off, 64);
        }
        sa = __shfl(sa, 0, 64);
        sp = __shfl(sp, 0, 64);
        dp = __shfl(dp, 0, 64);
        const float an = sqrtf(sa);
        const float inva = 1.0f / an;
        if (lane == 0) {
            float cp = dp / (an * sqrtf(sp));
            cp = fminf(1.f, fmaxf(-1.f, cp));
            acosP[r] = acosf(cp) * 10.0f;
            phoneA[r] = phone[b * TT + t];
        }
        // dims d = lane*4 .. +3: ks2=lane>>4, half=(lane>>3)&1, g=(lane>>1)&3, e=(lane&1)*4
        const unsigned u = pk4(a.x * inva, a.y * inva, a.z * inva, a.w * inva);
        unsigned char* ab = ancT + (size_t)(r >> 4) * 4096;
        *reinterpret_cast<unsigned*>(
            ab + ((((lane >> 4) * 4 + ((lane >> 1) & 3)) * 16 + (r & 15)) * 16)
               + ((lane >> 3) & 1) * 8 + (lane & 1) * 4) = u;
        return;
    }
    if (bid < 2560 + GH) {   // ---- ghist partial slice ----
        __shared__ unsigned h[128];
        const int s = bid - 2560;
        if (tid < 128) h[tid] = 0u;
        __syncthreads();
        const int base = s * (BT / GH);
        for (int i = tid; i < BT / GH; i += 256)
            atomicAdd(&h[phone[base + i] & 127], 1u);
        __syncthreads();
        if (tid < 128) ghp[s * 128 + tid] = h[tid];
        return;
    }
    {   // ---- zero cnt/flag ----
        const int i = (bid - 2592) * 256 + tid;
        if (i < BN) { cnt[i] = 0; flagA[i] = 0; }
    }
}

// ---------------------------------------------------------------------------
// Barrier-free GEMM pass (fp8 operands, full residency): 128 rows x 512 cols
// per block, 8 waves (4 row-groups x 2 col-groups). launch_bounds(512,8)
// requests 8 waves/EU = 4 blocks/CU resident (VGPR 44 leaves headroom).
// B frags read DIRECTLY from L1/L2 into registers; no s_barrier in hot loop.
// ---------------------------------------------------------------------------
__global__ __launch_bounds__(512, 8) void kpass(const long2v* __restrict__ ancTL,
                                                const long2v* __restrict__ negTL,
                                                const int* __restrict__ phoneT,
                                                const int* __restrict__ phoneA,
                                                float* __restrict__ list,
                                                int* __restrict__ cnt,
                                                int* __restrict__ flag) {
    __shared__ float candV[LCAP];
    __shared__ int candR[LCAP];
    __shared__ int s_nc;
    const int tid = threadIdx.x;
    const int w = tid >> 6;
    const int lane = tid & 63;
    const int g = lane >> 4;
    const int c = lane & 15;
    const int wr = w >> 1;              // row-group 0..3
    const int wc = w & 1;               // col-group 0..1
    // bijective XCD swizzle (1024 % 8 == 0): co-XCD blocks share ct slices
    const int logical = (blockIdx.x & 7) * 128 + (blockIdx.x >> 3);
    const int ct = logical >> 4;        // 0..63
    const int rt = logical & 15;        // 0..15
    const int row0 = rt * BROWS;
    const int colbase = ct * SLICE;

    if (tid == 0) s_nc = 0;

    long2v afp[2][4];
#pragma unroll
    for (int mt = 0; mt < 2; ++mt) {
        const int tile = rt * 8 + wr * 2 + mt;
#pragma unroll
        for (int ks2 = 0; ks2 < 4; ++ks2)
            afp[mt][ks2] = ancTL[tile * 256 + ks2 * 64 + lane];
    }
    int phA_r[2][4];
#pragma unroll
    for (int mt = 0; mt < 2; ++mt)
#pragma unroll
        for (int j = 0; j < 4; ++j)
            phA_r[mt][j] = phoneA[row0 + wr * 32 + mt * 16 + g * 4 + j];
    __syncthreads();   // s_nc visible

#pragma unroll 2
    for (int it = 0; it < NITER; ++it) {
        const int cb = colbase + it * 32 + wc * 16;   // wave's 16 cols
        const int cblk = cb >> 4;
        long2v bq[4];
#pragma unroll
        for (int ks2 = 0; ks2 < 4; ++ks2)
            bq[ks2] = negTL[cblk * 256 + ks2 * 64 + lane];
        const int ph = phoneT[cb + c];
        float4v acc0 = (float4v){0.f, 0.f, 0.f, 0.f};
        float4v acc1 = (float4v){0.f, 0.f, 0.f, 0.f};
        __builtin_amdgcn_s_setprio(1);
#pragma unroll
        for (int ks2 = 0; ks2 < 4; ++ks2) {
            acc0 = __builtin_amdgcn_mfma_f32_16x16x32_fp8_fp8(afp[0][ks2].x, bq[ks2].x, acc0, 0, 0, 0);
            acc1 = __builtin_amdgcn_mfma_f32_16x16x32_fp8_fp8(afp[1][ks2].x, bq[ks2].x, acc1, 0, 0, 0);
            acc0 = __builtin_amdgcn_mfma_f32_16x16x32_fp8_fp8(afp[0][ks2].y, bq[ks2].y, acc0, 0, 0, 0);
            acc1 = __builtin_amdgcn_mfma_f32_16x16x32_fp8_fp8(afp[1][ks2].y, bq[ks2].y, acc1, 0, 0, 0);
        }
        __builtin_amdgcn_s_setprio(0);
#pragma unroll
        for (int j = 0; j < 4; ++j) {
            float v0 = acc0[j];
            if (v0 < THETA && ph != phA_r[0][j]) {
                int k = atomicAdd(&s_nc, 1);
                if (k < LCAP) {
                    candV[k] = fmaxf(-1.f, v0);
                    candR[k] = row0 + wr * 32 + g * 4 + j;
                }
            }
            float v1 = acc1[j];
            if (v1 < THETA && ph != phA_r[1][j]) {
                int k = atomicAdd(&s_nc, 1);
                if (k < LCAP) {
                    candV[k] = fmaxf(-1.f, v1);
                    candR[k] = row0 + wr * 32 + 16 + g * 4 + j;
                }
            }
        }
    }

    __syncthreads();
    const int nc = s_nc;
    if (nc > LCAP) {   // astronomically unlikely: flag block rows for fallback
        for (int i = tid; i < BROWS; i += 512) flag[row0 + i] = 1;
    } else {
        for (int i = tid; i < nc; i += 512) {
            const int r = candR[i];
            int idx = atomicAdd(&cnt[r], 1);
            if (idx < CAP) list[(size_t)r * CAP + idx] = candV[i];
        }
    }
}

// ---------------------------------------------------------------------------
// per-row final: exact bottom-kp selection among candidates + exp/acos sum.
// ---------------------------------------------------------------------------
__global__ __launch_bounds__(64) void kfinal(const float* __restrict__ list,
                                             const int* __restrict__ cnt,
                                             const int* __restrict__ phoneA,
                                             const unsigned* __restrict__ ghp,
                                             const float* __restrict__ acosP,
                                             float* __restrict__ logits,
                                             int* __restrict__ flag) {
    __shared__ float sl[CAP];
    __shared__ unsigned subh[256];
    __shared__ float l2[128];
    __shared__ int s_b, s_cum, s_l2c;
    const int row = blockIdx.x;
    const int lane = threadIdx.x;
    const int mp = phoneA[row] & 127;
    int un = BT;
    for (int s = 0; s < GH; ++s) un -= (int)ghp[s * 128 + mp];
    const int kp = un < KTOP ? un : KTOP;
    const int c = cnt[row];
    if (kp <= 0) { if (lane == 0) logits[row] = acosP[row]; return; }
    if (c < kp || c > CAP) { if (lane == 0) flag[row] = 1; return; }

    for (int i = lane; i < c; i += 64) sl[i] = list[(size_t)row * CAP + i];
    for (int i = lane; i < 256; i += 64) subh[i] = 0u;
    if (lane == 0) s_l2c = 0;
    __syncthreads();

    for (int i = lane; i < c; i += 64) {
        int sb = (int)((sl[i] + 1.0f) * FSCALE);
        sb = sb < 0 ? 0 : (sb > 255 ? 255 : sb);
        atomicAdd(&subh[sb], 1u);
    }
    __syncthreads();
    if (lane == 0) {
        unsigned cum = 0;
        int b = 0;
        for (; b < 256; ++b) {
            if (cum + subh[b] >= (unsigned)kp) break;
            cum += subh[b];
        }
        s_b = b > 255 ? 255 : b;
        s_cum = (int)cum;
    }
    __syncthreads();
    const int bs = s_b, cum = s_cum;

    float ls = 0.f;
    for (int i = lane; i < c; i += 64) {
        float v = sl[i];
        int sb = (int)((v + 1.0f) * FSCALE);
        sb = sb < 0 ? 0 : (sb > 255 ? 255 : sb);
        if (sb < bs) {
            ls += expf(acosf(fminf(1.f, fmaxf(-1.f, v))) * 10.0f);
        } else if (sb == bs) {
            int k = atomicAdd(&s_l2c, 1);
            if (k < 128) l2[k] = v;
        }
    }
#pragma unroll
    for (int off = 1; off < 64; off <<= 1) ls += __shfl_xor(ls, off, 64);
    __syncthreads();
    const int n2 = s_l2c;
    if (n2 > 128) { if (lane == 0) flag[row] = 1; return; }

    float den = ls;
    int rem = kp - cum;
    if (rem > n2) rem = n2;
    float v0 = lane < n2 ? l2[lane] : 1e30f;
    float v1 = lane + 64 < n2 ? l2[lane + 64] : 1e30f;
    for (int it = 0; it < rem; ++it) {
        float mv = fminf(v0, v1);
        int mi = (v1 < v0) ? lane + 64 : lane;
#pragma unroll
        for (int off = 1; off < 64; off <<= 1) {
            float ov = __shfl_xor(mv, off, 64);
            int oi = __shfl_xor(mi, off, 64);
            if (ov < mv || (ov == mv && oi < mi)) { mv = ov; mi = oi; }
        }
        den += expf(acosf(fminf(1.f, fmaxf(-1.f, mv))) * 10.0f);
        if (mi == lane) v0 = 1e30f;
        if (mi == lane + 64) v1 = 1e30f;
    }
    if (lane == 0) logits[row] = acosP[row] - logf(den);
}

// ---------------------------------------------------------------------------
// exact fallback for flagged rows (cold path, never expected).
// ---------------------------------------------------------------------------
__global__ __launch_bounds__(256) void kfallback(const float* __restrict__ ctx,
                                                 const float* __restrict__ tgt,
                                                 const int* __restrict__ mask_index,
                                                 const int* __restrict__ phone,
                                                 const int* __restrict__ flag,
                                                 const unsigned* __restrict__ ghp,
                                                 const float* __restrict__ acosP,
                                                 float* __restrict__ logits) {
    const int row = blockIdx.x;
    if (!flag[row]) return;
    __shared__ float anc[TD];
    __shared__ float redf[256];
    __shared__ int redi[256];
    __shared__ unsigned hist[2048];
    __shared__ float lst[512];
    __shared__ int s_b, s_cum, s_lc;
    const int tid = threadIdx.x;
    const int b = row >> 7;
    const int t = mask_index[row & 127];
    const int mp = phone[b * TT + t];

    {
        float x = ctx[((size_t)b * TT + t) * TD + tid];
        redf[tid] = x * x;
        anc[tid] = x;
        __syncthreads();
        for (int s = 128; s > 0; s >>= 1) {
            if (tid < s) redf[tid] += redf[tid + s];
            __syncthreads();
        }
        float inv = 1.0f / sqrtf(redf[0]);
        __syncthreads();
        anc[tid] *= inv;
    }
    for (int i = tid; i < 2048; i += 256) hist[i] = 0u;
    if (tid == 0) s_lc = 0;
    __syncthreads();

    int un = BT;
    for (int s = 0; s < GH; ++s) un -= (int)ghp[s * 128 + (mp & 127)];
    const int kp = un < KTOP ? un : KTOP;
    if (kp <= 0) { if (tid == 0) logits[row] = acosP[row]; return; }

    for (int col = tid; col < BT; col += 256) {
        if (phone[col] == mp) continue;
        const float* nr = tgt + (size_t)col * TD;
        float dot = 0.f, sq = 0.f;
        for (int d = 0; d < TD; d += 4) {
            float4 v = *reinterpret_cast<const float4*>(nr + d);
            dot += anc[d] * v.x + anc[d + 1] * v.y + anc[d + 2] * v.z + anc[d + 3] * v.w;
            sq += v.x * v.x + v.y * v.y + v.z * v.z + v.w * v.w;
        }
        float cv = fminf(1.f, fmaxf(-1.f, dot / sqrtf(sq)));
        int bb = (int)((cv + 1.0f) * 1024.0f);
        bb = bb > 2047 ? 2047 : bb;
        atomicAdd(&hist[bb], 1u);
    }
    __syncthreads();
    if (tid == 0) {
        unsigned cum = 0;
        int bb = 0;
        for (; bb < 2048; ++bb) {
            if (cum + hist[bb] >= (unsigned)kp) break;
            cum += hist[bb];
        }
        s_b = bb > 2047 ? 2047 : bb;
        s_cum = (int)cum;
    }
    __syncthreads();
    const int bs = s_b;

    float ls = 0.f;
    for (int col = tid; col < BT; col += 256) {
        if (phone[col] == mp) continue;
        const float* nr = tgt + (size_t)col * TD;
        float dot = 0.f, sq = 0.f;
        for (int d = 0; d < TD; d += 4) {
            float4 v = *reinterpret_cast<const float4*>(nr + d);
            dot += anc[d] * v.x + anc[d + 1] * v.y + anc[d + 2] * v.z + anc[d + 3] * v.w;
            sq += v.x * v.x + v.y * v.y + v.z * v.z + v.w * v.w;
        }
        float cv = fminf(1.f, fmaxf(-1.f, dot / sqrtf(sq)));
        int bb = (int)((cv + 1.0f) * 1024.0f);
        bb = bb > 2047 ? 2047 : bb;
        if (bb < bs) {
            ls += expf(acosf(cv) * 10.0f);
        } else if (bb == bs) {
            int k = atomicAdd(&s_lc, 1);
            if (k < 512) lst[k] = cv;
        }
    }
    redf[tid] = ls;
    __syncthreads();
    for (int s = 128; s > 0; s >>= 1) {
        if (tid < s) redf[tid] += redf[tid + s];
        __syncthreads();
    }
    float den = redf[0];
    __syncthreads();

    int lc = s_lc < 512 ? s_lc : 512;
    int rem = kp - s_cum;
    if (rem > lc) rem = lc;
    for (int it = 0; it < rem; ++it) {
        float mv = 1e30f;
        int mi = -1;
        for (int i = tid; i < lc; i += 256) {
            if (lst[i] < mv) { mv = lst[i]; mi = i; }
        }
        redf[tid] = mv;
        redi[tid] = mi;
        __syncthreads();
        for (int s = 128; s > 0; s >>= 1) {
            if (tid < s && (redf[tid + s] < redf[tid] ||
                            (redf[tid + s] == redf[tid] && redi[tid + s] >= 0 &&
                             (redi[tid] < 0 || redi[tid + s] < redi[tid])))) {
                redf[tid] = redf[tid + s];
                redi[tid] = redi[tid + s];
            }
            __syncthreads();
        }
        if (tid == 0) {
            den += expf(acosf(fminf(1.f, fmaxf(-1.f, redf[0]))) * 10.0f);
            if (redi[0] >= 0) lst[redi[0]] = 1e30f;
            redf[0] = den;
        }
        __syncthreads();
        den = redf[0];
        __syncthreads();
    }
    if (tid == 0) logits[row] = acosP[row] - logf(den);
}

__global__ __launch_bounds__(256) void kloss(const float* __restrict__ logits,
                                             float* __restrict__ out) {
    __shared__ float red[256];
    int tid = threadIdx.x;
    float s = 0.f;
    for (int i = tid; i < BN; i += 256) s += logits[i];
    red[tid] = s;
    __syncthreads();
    for (int st = 128; st > 0; st >>= 1) {
        if (tid < st) red[tid] += red[tid + st];
        __syncthreads();
    }
    if (tid == 0) out[0] = -red[0] / (float)BN;
}

extern "C" void kernel_launch(void* const* d_in, const int* in_sizes, int n_in,
                              void* d_out, int out_size, void* d_ws, size_t ws_size,
                              hipStream_t stream) {
    (void)in_sizes; (void)n_in; (void)out_size; (void)ws_size;
    const float* ctx   = (const float*)d_in[0];
    const float* tgt   = (const float*)d_in[1];
    const int*   mask  = (const int*)d_in[2];
    const int*   phone = (const int*)d_in[3];
    float* out = (float*)d_out;

    char* p = (char*)d_ws;
    unsigned char* negT = (unsigned char*)p;              p += (size_t)BT * TD;       // 8 MB
    unsigned char* ancT = (unsigned char*)p;              p += (size_t)BN * TD;       // 512 KB
    float* acosP  = (float*)p;                            p += (size_t)BN * 4;
    int*   phoneA = (int*)p;                              p += (size_t)BN * 4;
    int*   cntA   = (int*)p;                              p += (size_t)BN * 4;
    int*   flagA  = (int*)p;                              p += (size_t)BN * 4;
    unsigned* ghp = (unsigned*)p;                         p += (size_t)GH * 128 * 4;
    float* listA  = (float*)p;                            p += (size_t)BN * CAP * 4;  // 8 MB
    float* logits = (float*)p;                            p += (size_t)BN * 4;

    kinit<<<2600, 256, 0, stream>>>(ctx, tgt, mask, phone, negT, ancT,
                                    acosP, phoneA, ghp, cntA, flagA);
    kpass<<<1024, 512, 0, stream>>>((const long2v*)ancT, (const long2v*)negT,
                                    phone, phoneA, listA, cntA, flagA);
    kfinal<<<BN, 64, 0, stream>>>(listA, cntA, phoneA, ghp, acosP, logits, flagA);
    kfallback<<<BN, 256, 0, stream>>>(ctx, tgt, mask, phone, flagA, ghp, acosP, logits);
    kloss<<<1, 256, 0, stream>>>(logits, out);
}

// Round 18
// 117.514 us; speedup vs baseline: 1.3687x; 1.3687x over previous
//
#include <hip/hip_runtime.h>
#include <math.h>

#define TT 2048
#define TD 256
#define BN 2048
#define BT 32768
#define KTOP 100
#define CAP 1024     // per-row global candidate list capacity
#define LCAP 1024    // per-block LDS candidate buffer
#define THETA -0.15f // candidate threshold on cos
#define BROWS 128    // rows per block (4 row-groups x 32)
#define SLICE 512    // cols per block
#define NITER 16     // SLICE / 32 (32 cols per iter: 2 col-groups x 16)
#define FSCALE 301.176470588f  // 256 / 0.85 (kfinal bins over [-1, THETA))
#define GH 32        // ghist partial slices

typedef __attribute__((ext_vector_type(4))) float float4v;
typedef __attribute__((ext_vector_type(2))) long long2v;

// pack 4 floats -> 4 fp8 (e4m3, HW cvt; same format the fp8 MFMA consumes)
__device__ __forceinline__ unsigned pk4(float a, float b, float c, float d) {
    int u = __builtin_amdgcn_cvt_pk_fp8_f32(a, b, 0, false);
    u = __builtin_amdgcn_cvt_pk_fp8_f32(c, d, u, true);
    return (unsigned)u;
}

// fp8 fragment-tiled layout, per 16-col/row block (4096 B):
//   [ks2(4)][g(4)][c(16)][16B = ks-even 8B | ks-odd 8B]
// dim d -> ks = d>>5, ks2 = ks>>1, half = ks&1, g = (d>>3)&3, e = d&7
// kpass loads one long2 per (ks2, lane): cblk*256 + ks2*64 + lane.

// ---------------------------------------------------------------------------
// Fused init kernel. Block ranges:
//   [0, 2048)      : kprep — normalize 16 negatives, store fp8 fragment-tiled
//   [2048, 2560)   : kanchor — 4 anchor rows per block (fp8 tiled + fp32 num)
//   [2560, 2592)   : ghist partial slices
//   [2592, 2600)   : zero cnt/flag
// ---------------------------------------------------------------------------
__global__ __launch_bounds__(256) void kinit(const float* __restrict__ ctx,
                                             const float* __restrict__ tgt,
                                             const int* __restrict__ mask_index,
                                             const int* __restrict__ phone,
                                             unsigned char* __restrict__ negT,
                                             unsigned char* __restrict__ ancT,
                                             float* __restrict__ acosP,
                                             int* __restrict__ phoneA,
                                             unsigned* __restrict__ ghp,
                                             int* __restrict__ cnt,
                                             int* __restrict__ flagA) {
    const int bid = blockIdx.x;
    const int tid = threadIdx.x;

    if (bid < 2048) {   // ---- kprep: colblk bid, 16 cols, barrier-free ----
        const int col = tid >> 4;     // 0..15 within colblk
        const int seg = tid & 15;     // dims [seg*16, seg*16+16)
        const float* src = tgt + ((size_t)bid * 16 + col) * TD + seg * 16;
        float4 v0 = *reinterpret_cast<const float4*>(src + 0);
        float4 v1 = *reinterpret_cast<const float4*>(src + 4);
        float4 v2 = *reinterpret_cast<const float4*>(src + 8);
        float4 v3 = *reinterpret_cast<const float4*>(src + 12);
        float s = v0.x * v0.x + v0.y * v0.y + v0.z * v0.z + v0.w * v0.w
                + v1.x * v1.x + v1.y * v1.y + v1.z * v1.z + v1.w * v1.w
                + v2.x * v2.x + v2.y * v2.y + v2.z * v2.z + v2.w * v2.w
                + v3.x * v3.x + v3.y * v3.y + v3.z * v3.z + v3.w * v3.w;
        s += __shfl_xor(s, 1, 64);
        s += __shfl_xor(s, 2, 64);
        s += __shfl_xor(s, 4, 64);
        s += __shfl_xor(s, 8, 64);
        const float iv = 1.0f / sqrtf(s);
        const int ks2 = seg >> 2;
        const int half = (seg >> 1) & 1;
        const int ga = (seg * 2) & 3;
        const int gb = (seg * 2 + 1) & 3;
        unsigned char* base = negT + (size_t)bid * 4096;
        uint2 pa, pb;
        pa.x = pk4(v0.x * iv, v0.y * iv, v0.z * iv, v0.w * iv);
        pa.y = pk4(v1.x * iv, v1.y * iv, v1.z * iv, v1.w * iv);
        pb.x = pk4(v2.x * iv, v2.y * iv, v2.z * iv, v2.w * iv);
        pb.y = pk4(v3.x * iv, v3.y * iv, v3.z * iv, v3.w * iv);
        *reinterpret_cast<uint2*>(base + (((ks2 * 4 + ga) * 16 + col) * 16) + half * 8) = pa;
        *reinterpret_cast<uint2*>(base + (((ks2 * 4 + gb) * 16 + col) * 16) + half * 8) = pb;
        return;
    }
    if (bid < 2560) {   // ---- kanchor: rows (bid-2048)*4 .. +3 ----
        const int r = (bid - 2048) * 4 + (tid >> 6);
        const int lane = tid & 63;
        const int b = r >> 7;
        const int n = r & 127;
        const int t = mask_index[n];
        const size_t base = ((size_t)b * TT + t) * TD;
        float4 a = *reinterpret_cast<const float4*>(ctx + base + lane * 4);
        float4 p = *reinterpret_cast<const float4*>(tgt + base + lane * 4);
        float sa = a.x * a.x + a.y * a.y + a.z * a.z + a.w * a.w;
        float sp = p.x * p.x + p.y * p.y + p.z * p.z + p.w * p.w;
        float dp = a.x * p.x + a.y * p.y + a.z * p.z + a.w * p.w;
        for (int off = 32; off > 0; off >>= 1) {
            sa += __shfl_down(sa, off, 64);
            sp += __shfl_down(sp, off, 64);
            dp += __shfl_down(dp, off, 64);
        }
        sa = __shfl(sa, 0, 64);
        sp = __shfl(sp, 0, 64);
        dp = __shfl(dp, 0, 64);
        const float an = sqrtf(sa);
        const float inva = 1.0f / an;
        if (lane == 0) {
            float cp = dp / (an * sqrtf(sp));
            cp = fminf(1.f, fmaxf(-1.f, cp));
            acosP[r] = acosf(cp) * 10.0f;
            phoneA[r] = phone[b * TT + t];
        }
        // dims d = lane*4 .. +3: ks2=lane>>4, half=(lane>>3)&1, g=(lane>>1)&3, e=(lane&1)*4
        const unsigned u = pk4(a.x * inva, a.y * inva, a.z * inva, a.w * inva);
        unsigned char* ab = ancT + (size_t)(r >> 4) * 4096;
        *reinterpret_cast<unsigned*>(
            ab + ((((lane >> 4) * 4 + ((lane >> 1) & 3)) * 16 + (r & 15)) * 16)
               + ((lane >> 3) & 1) * 8 + (lane & 1) * 4) = u;
        return;
    }
    if (bid < 2560 + GH) {   // ---- ghist partial slice ----
        __shared__ unsigned h[128];
        const int s = bid - 2560;
        if (tid < 128) h[tid] = 0u;
        __syncthreads();
        const int base = s * (BT / GH);
        for (int i = tid; i < BT / GH; i += 256)
            atomicAdd(&h[phone[base + i] & 127], 1u);
        __syncthreads();
        if (tid < 128) ghp[s * 128 + tid] = h[tid];
        return;
    }
    {   // ---- zero cnt/flag ----
        const int i = (bid - 2592) * 256 + tid;
        if (i < BN) { cnt[i] = 0; flagA[i] = 0; }
    }
}

// ---------------------------------------------------------------------------
// Barrier-free GEMM pass (fp8 operands, R16 config — measured best):
// 128 rows x 512 cols per block, 8 waves (4 row-groups x 2 col-groups).
// launch_bounds(512,4): 2 blocks/CU with VGPR 44 — register-resident
// operands beat higher occupancy (R17's (512,8) starved regalloc: VGPR 32,
// FETCH 3.5x, +68% time). B frags read DIRECTLY from L1/L2 into registers;
// mfma_f32_16x16x32_fp8_fp8 at the bf16 rate; no s_barrier in hot loop.
// ---------------------------------------------------------------------------
__global__ __launch_bounds__(512, 4) void kpass(const long2v* __restrict__ ancTL,
                                                const long2v* __restrict__ negTL,
                                                const int* __restrict__ phoneT,
                                                const int* __restrict__ phoneA,
                                                float* __restrict__ list,
                                                int* __restrict__ cnt,
                                                int* __restrict__ flag) {
    __shared__ float candV[LCAP];
    __shared__ int candR[LCAP];
    __shared__ int s_nc;
    const int tid = threadIdx.x;
    const int w = tid >> 6;
    const int lane = tid & 63;
    const int g = lane >> 4;
    const int c = lane & 15;
    const int wr = w >> 1;              // row-group 0..3
    const int wc = w & 1;               // col-group 0..1
    // bijective XCD swizzle (1024 % 8 == 0): co-XCD blocks share ct slices
    const int logical = (blockIdx.x & 7) * 128 + (blockIdx.x >> 3);
    const int ct = logical >> 4;        // 0..63
    const int rt = logical & 15;        // 0..15
    const int row0 = rt * BROWS;
    const int colbase = ct * SLICE;

    if (tid == 0) s_nc = 0;

    long2v afp[2][4];
#pragma unroll
    for (int mt = 0; mt < 2; ++mt) {
        const int tile = rt * 8 + wr * 2 + mt;
#pragma unroll
        for (int ks2 = 0; ks2 < 4; ++ks2)
            afp[mt][ks2] = ancTL[tile * 256 + ks2 * 64 + lane];
    }
    int phA_r[2][4];
#pragma unroll
    for (int mt = 0; mt < 2; ++mt)
#pragma unroll
        for (int j = 0; j < 4; ++j)
            phA_r[mt][j] = phoneA[row0 + wr * 32 + mt * 16 + g * 4 + j];
    __syncthreads();   // s_nc visible

#pragma unroll 2
    for (int it = 0; it < NITER; ++it) {
        const int cb = colbase + it * 32 + wc * 16;   // wave's 16 cols
        const int cblk = cb >> 4;
        long2v bq[4];
#pragma unroll
        for (int ks2 = 0; ks2 < 4; ++ks2)
            bq[ks2] = negTL[cblk * 256 + ks2 * 64 + lane];
        const int ph = phoneT[cb + c];
        float4v acc0 = (float4v){0.f, 0.f, 0.f, 0.f};
        float4v acc1 = (float4v){0.f, 0.f, 0.f, 0.f};
        __builtin_amdgcn_s_setprio(1);
#pragma unroll
        for (int ks2 = 0; ks2 < 4; ++ks2) {
            acc0 = __builtin_amdgcn_mfma_f32_16x16x32_fp8_fp8(afp[0][ks2].x, bq[ks2].x, acc0, 0, 0, 0);
            acc1 = __builtin_amdgcn_mfma_f32_16x16x32_fp8_fp8(afp[1][ks2].x, bq[ks2].x, acc1, 0, 0, 0);
            acc0 = __builtin_amdgcn_mfma_f32_16x16x32_fp8_fp8(afp[0][ks2].y, bq[ks2].y, acc0, 0, 0, 0);
            acc1 = __builtin_amdgcn_mfma_f32_16x16x32_fp8_fp8(afp[1][ks2].y, bq[ks2].y, acc1, 0, 0, 0);
        }
        __builtin_amdgcn_s_setprio(0);
#pragma unroll
        for (int j = 0; j < 4; ++j) {
            float v0 = acc0[j];
            if (v0 < THETA && ph != phA_r[0][j]) {
                int k = atomicAdd(&s_nc, 1);
                if (k < LCAP) {
                    candV[k] = fmaxf(-1.f, v0);
                    candR[k] = row0 + wr * 32 + g * 4 + j;
                }
            }
            float v1 = acc1[j];
            if (v1 < THETA && ph != phA_r[1][j]) {
                int k = atomicAdd(&s_nc, 1);
                if (k < LCAP) {
                    candV[k] = fmaxf(-1.f, v1);
                    candR[k] = row0 + wr * 32 + 16 + g * 4 + j;
                }
            }
        }
    }

    __syncthreads();
    const int nc = s_nc;
    if (nc > LCAP) {   // astronomically unlikely: flag block rows for fallback
        for (int i = tid; i < BROWS; i += 512) flag[row0 + i] = 1;
    } else {
        for (int i = tid; i < nc; i += 512) {
            const int r = candR[i];
            int idx = atomicAdd(&cnt[r], 1);
            if (idx < CAP) list[(size_t)r * CAP + idx] = candV[i];
        }
    }
}

// ---------------------------------------------------------------------------
// per-row final: exact bottom-kp selection among candidates + exp/acos sum.
// ---------------------------------------------------------------------------
__global__ __launch_bounds__(64) void kfinal(const float* __restrict__ list,
                                             const int* __restrict__ cnt,
                                             const int* __restrict__ phoneA,
                                             const unsigned* __restrict__ ghp,
                                             const float* __restrict__ acosP,
                                             float* __restrict__ logits,
                                             int* __restrict__ flag) {
    __shared__ float sl[CAP];
    __shared__ unsigned subh[256];
    __shared__ float l2[128];
    __shared__ int s_b, s_cum, s_l2c;
    const int row = blockIdx.x;
    const int lane = threadIdx.x;
    const int mp = phoneA[row] & 127;
    int un = BT;
    for (int s = 0; s < GH; ++s) un -= (int)ghp[s * 128 + mp];
    const int kp = un < KTOP ? un : KTOP;
    const int c = cnt[row];
    if (kp <= 0) { if (lane == 0) logits[row] = acosP[row]; return; }
    if (c < kp || c > CAP) { if (lane == 0) flag[row] = 1; return; }

    for (int i = lane; i < c; i += 64) sl[i] = list[(size_t)row * CAP + i];
    for (int i = lane; i < 256; i += 64) subh[i] = 0u;
    if (lane == 0) s_l2c = 0;
    __syncthreads();

    for (int i = lane; i < c; i += 64) {
        int sb = (int)((sl[i] + 1.0f) * FSCALE);
        sb = sb < 0 ? 0 : (sb > 255 ? 255 : sb);
        atomicAdd(&subh[sb], 1u);
    }
    __syncthreads();
    if (lane == 0) {
        unsigned cum = 0;
        int b = 0;
        for (; b < 256; ++b) {
            if (cum + subh[b] >= (unsigned)kp) break;
            cum += subh[b];
        }
        s_b = b > 255 ? 255 : b;
        s_cum = (int)cum;
    }
    __syncthreads();
    const int bs = s_b, cum = s_cum;

    float ls = 0.f;
    for (int i = lane; i < c; i += 64) {
        float v = sl[i];
        int sb = (int)((v + 1.0f) * FSCALE);
        sb = sb < 0 ? 0 : (sb > 255 ? 255 : sb);
        if (sb < bs) {
            ls += expf(acosf(fminf(1.f, fmaxf(-1.f, v))) * 10.0f);
        } else if (sb == bs) {
            int k = atomicAdd(&s_l2c, 1);
            if (k < 128) l2[k] = v;
        }
    }
#pragma unroll
    for (int off = 1; off < 64; off <<= 1) ls += __shfl_xor(ls, off, 64);
    __syncthreads();
    const int n2 = s_l2c;
    if (n2 > 128) { if (lane == 0) flag[row] = 1; return; }

    float den = ls;
    int rem = kp - cum;
    if (rem > n2) rem = n2;
    float v0 = lane < n2 ? l2[lane] : 1e30f;
    float v1 = lane + 64 < n2 ? l2[lane + 64] : 1e30f;
    for (int it = 0; it < rem; ++it) {
        float mv = fminf(v0, v1);
        int mi = (v1 < v0) ? lane + 64 : lane;
#pragma unroll
        for (int off = 1; off < 64; off <<= 1) {
            float ov = __shfl_xor(mv, off, 64);
            int oi = __shfl_xor(mi, off, 64);
            if (ov < mv || (ov == mv && oi < mi)) { mv = ov; mi = oi; }
        }
        den += expf(acosf(fminf(1.f, fmaxf(-1.f, mv))) * 10.0f);
        if (mi == lane) v0 = 1e30f;
        if (mi == lane + 64) v1 = 1e30f;
    }
    if (lane == 0) logits[row] = acosP[row] - logf(den);
}

// ---------------------------------------------------------------------------
// exact fallback for flagged rows (cold path, never expected).
// ---------------------------------------------------------------------------
__global__ __launch_bounds__(256) void kfallback(const float* __restrict__ ctx,
                                                 const float* __restrict__ tgt,
                                                 const int* __restrict__ mask_index,
                                                 const int* __restrict__ phone,
                                                 const int* __restrict__ flag,
                                                 const unsigned* __restrict__ ghp,
                                                 const float* __restrict__ acosP,
                                                 float* __restrict__ logits) {
    const int row = blockIdx.x;
    if (!flag[row]) return;
    __shared__ float anc[TD];
    __shared__ float redf[256];
    __shared__ int redi[256];
    __shared__ unsigned hist[2048];
    __shared__ float lst[512];
    __shared__ int s_b, s_cum, s_lc;
    const int tid = threadIdx.x;
    const int b = row >> 7;
    const int t = mask_index[row & 127];
    const int mp = phone[b * TT + t];

    {
        float x = ctx[((size_t)b * TT + t) * TD + tid];
        redf[tid] = x * x;
        anc[tid] = x;
        __syncthreads();
        for (int s = 128; s > 0; s >>= 1) {
            if (tid < s) redf[tid] += redf[tid + s];
            __syncthreads();
        }
        float inv = 1.0f / sqrtf(redf[0]);
        __syncthreads();
        anc[tid] *= inv;
    }
    for (int i = tid; i < 2048; i += 256) hist[i] = 0u;
    if (tid == 0) s_lc = 0;
    __syncthreads();

    int un = BT;
    for (int s = 0; s < GH; ++s) un -= (int)ghp[s * 128 + (mp & 127)];
    const int kp = un < KTOP ? un : KTOP;
    if (kp <= 0) { if (tid == 0) logits[row] = acosP[row]; return; }

    for (int col = tid; col < BT; col += 256) {
        if (phone[col] == mp) continue;
        const float* nr = tgt + (size_t)col * TD;
        float dot = 0.f, sq = 0.f;
        for (int d = 0; d < TD; d += 4) {
            float4 v = *reinterpret_cast<const float4*>(nr + d);
            dot += anc[d] * v.x + anc[d + 1] * v.y + anc[d + 2] * v.z + anc[d + 3] * v.w;
            sq += v.x * v.x + v.y * v.y + v.z * v.z + v.w * v.w;
        }
        float cv = fminf(1.f, fmaxf(-1.f, dot / sqrtf(sq)));
        int bb = (int)((cv + 1.0f) * 1024.0f);
        bb = bb > 2047 ? 2047 : bb;
        atomicAdd(&hist[bb], 1u);
    }
    __syncthreads();
    if (tid == 0) {
        unsigned cum = 0;
        int bb = 0;
        for (; bb < 2048; ++bb) {
            if (cum + hist[bb] >= (unsigned)kp) break;
            cum += hist[bb];
        }
        s_b = bb > 2047 ? 2047 : bb;
        s_cum = (int)cum;
    }
    __syncthreads();
    const int bs = s_b;

    float ls = 0.f;
    for (int col = tid; col < BT; col += 256) {
        if (phone[col] == mp) continue;
        const float* nr = tgt + (size_t)col * TD;
        float dot = 0.f, sq = 0.f;
        for (int d = 0; d < TD; d += 4) {
            float4 v = *reinterpret_cast<const float4*>(nr + d);
            dot += anc[d] * v.x + anc[d + 1] * v.y + anc[d + 2] * v.z + anc[d + 3] * v.w;
            sq += v.x * v.x + v.y * v.y + v.z * v.z + v.w * v.w;
        }
        float cv = fminf(1.f, fmaxf(-1.f, dot / sqrtf(sq)));
        int bb = (int)((cv + 1.0f) * 1024.0f);
        bb = bb > 2047 ? 2047 : bb;
        if (bb < bs) {
            ls += expf(acosf(cv) * 10.0f);
        } else if (bb == bs) {
            int k = atomicAdd(&s_lc, 1);
            if (k < 512) lst[k] = cv;
        }
    }
    redf[tid] = ls;
    __syncthreads();
    for (int s = 128; s > 0; s >>= 1) {
        if (tid < s) redf[tid] += redf[tid + s];
        __syncthreads();
    }
    float den = redf[0];
    __syncthreads();

    int lc = s_lc < 512 ? s_lc : 512;
    int rem = kp - s_cum;
    if (rem > lc) rem = lc;
    for (int it = 0; it < rem; ++it) {
        float mv = 1e30f;
        int mi = -1;
        for (int i = tid; i < lc; i += 256) {
            if (lst[i] < mv) { mv = lst[i]; mi = i; }
        }
        redf[tid] = mv;
        redi[tid] = mi;
        __syncthreads();
        for (int s = 128; s > 0; s >>= 1) {
            if (tid < s && (redf[tid + s] < redf[tid] ||
                            (redf[tid + s] == redf[tid] && redi[tid + s] >= 0 &&
                             (redi[tid] < 0 || redi[tid + s] < redi[tid])))) {
                redf[tid] = redf[tid + s];
                redi[tid] = redi[tid + s];
            }
            __syncthreads();
        }
        if (tid == 0) {
            den += expf(acosf(fminf(1.f, fmaxf(-1.f, redf[0]))) * 10.0f);
            if (redi[0] >= 0) lst[redi[0]] = 1e30f;
            redf[0] = den;
        }
        __syncthreads();
        den = redf[0];
        __syncthreads();
    }
    if (tid == 0) logits[row] = acosP[row] - logf(den);
}

__global__ __launch_bounds__(256) void kloss(const float* __restrict__ logits,
                                             float* __restrict__ out) {
    __shared__ float red[256];
    int tid = threadIdx.x;
    float s = 0.f;
    for (int i = tid; i < BN; i += 256) s += logits[i];
    red[tid] = s;
    __syncthreads();
    for (int st = 128; st > 0; st >>= 1) {
        if (tid < st) red[tid] += red[tid + st];
        __syncthreads();
    }
    if (tid == 0) out[0] = -red[0] / (float)BN;
}

extern "C" void kernel_launch(void* const* d_in, const int* in_sizes, int n_in,
                              void* d_out, int out_size, void* d_ws, size_t ws_size,
                              hipStream_t stream) {
    (void)in_sizes; (void)n_in; (void)out_size; (void)ws_size;
    const float* ctx   = (const float*)d_in[0];
    const float* tgt   = (const float*)d_in[1];
    const int*   mask  = (const int*)d_in[2];
    const int*   phone = (const int*)d_in[3];
    float* out = (float*)d_out;

    char* p = (char*)d_ws;
    unsigned char* negT = (unsigned char*)p;              p += (size_t)BT * TD;       // 8 MB
    unsigned char* ancT = (unsigned char*)p;              p += (size_t)BN * TD;       // 512 KB
    float* acosP  = (float*)p;                            p += (size_t)BN * 4;
    int*   phoneA = (int*)p;                              p += (size_t)BN * 4;
    int*   cntA   = (int*)p;                              p += (size_t)BN * 4;
    int*   flagA  = (int*)p;                              p += (size_t)BN * 4;
    unsigned* ghp = (unsigned*)p;                         p += (size_t)GH * 128 * 4;
    float* listA  = (float*)p;                            p += (size_t)BN * CAP * 4;  // 8 MB
    float* logits = (float*)p;                            p += (size_t)BN * 4;

    kinit<<<2600, 256, 0, stream>>>(ctx, tgt, mask, phone, negT, ancT,
                                    acosP, phoneA, ghp, cntA, flagA);
    kpass<<<1024, 512, 0, stream>>>((const long2v*)ancT, (const long2v*)negT,
                                    phone, phoneA, listA, cntA, flagA);
    kfinal<<<BN, 64, 0, stream>>>(listA, cntA, phoneA, ghp, acosP, logits, flagA);
    kfallback<<<BN, 256, 0, stream>>>(ctx, tgt, mask, phone, flagA, ghp, acosP, logits);
    kloss<<<1, 256, 0, stream>>>(logits, out);
}

// Round 19
// 117.138 us; speedup vs baseline: 1.3731x; 1.0032x over previous
//
#include <hip/hip_runtime.h>
#include <math.h>

#define TT 2048
#define TD 256
#define BN 2048
#define BT 32768
#define KTOP 100
#define CAP 1024     // per-row global candidate list capacity
#define LCAP 1024    // per-block LDS candidate buffer
#define THETA -0.15f // candidate threshold on cos
#define BROWS 128    // rows per block (4 row-groups x 32)
#define SLICE 512    // cols per block
#define NITER 16     // SLICE / 32 (32 cols per iter: 2 col-groups x 16)
#define FSCALE 301.176470588f  // 256 / 0.85 (kfinal bins over [-1, THETA))
#define GH 32        // ghist partial slices

typedef __attribute__((ext_vector_type(4))) float float4v;
typedef __attribute__((ext_vector_type(2))) long long2v;

// pack 4 floats -> 4 fp8 (e4m3, HW cvt; same format the fp8 MFMA consumes)
__device__ __forceinline__ unsigned pk4(float a, float b, float c, float d) {
    int u = __builtin_amdgcn_cvt_pk_fp8_f32(a, b, 0, false);
    u = __builtin_amdgcn_cvt_pk_fp8_f32(c, d, u, true);
    return (unsigned)u;
}

// fp8 fragment-tiled layout, per 16-col/row block (4096 B):
//   [ks2(4)][g(4)][c(16)][16B = ks-even 8B | ks-odd 8B]
// dim d -> ks = d>>5, ks2 = ks>>1, half = ks&1, g = (d>>3)&3, e = d&7
// kpass loads one long2 per (ks2, lane): cblk*256 + ks2*64 + lane.

// ---------------------------------------------------------------------------
// Fused init kernel. Block ranges:
//   [0, 2048)      : kprep — normalize 16 negatives, store fp8 fragment-tiled
//   [2048, 2560)   : kanchor — 4 anchor rows per block (fp8 tiled + fp32 num)
//   [2560, 2592)   : ghist partial slices
//   [2592, 2600)   : zero cnt/flag
// ---------------------------------------------------------------------------
__global__ __launch_bounds__(256) void kinit(const float* __restrict__ ctx,
                                             const float* __restrict__ tgt,
                                             const int* __restrict__ mask_index,
                                             const int* __restrict__ phone,
                                             unsigned char* __restrict__ negT,
                                             unsigned char* __restrict__ ancT,
                                             float* __restrict__ acosP,
                                             int* __restrict__ phoneA,
                                             unsigned* __restrict__ ghp,
                                             int* __restrict__ cnt,
                                             int* __restrict__ flagA) {
    const int bid = blockIdx.x;
    const int tid = threadIdx.x;

    if (bid < 2048) {   // ---- kprep: colblk bid, 16 cols, barrier-free ----
        const int col = tid >> 4;     // 0..15 within colblk
        const int seg = tid & 15;     // dims [seg*16, seg*16+16)
        const float* src = tgt + ((size_t)bid * 16 + col) * TD + seg * 16;
        float4 v0 = *reinterpret_cast<const float4*>(src + 0);
        float4 v1 = *reinterpret_cast<const float4*>(src + 4);
        float4 v2 = *reinterpret_cast<const float4*>(src + 8);
        float4 v3 = *reinterpret_cast<const float4*>(src + 12);
        float s = v0.x * v0.x + v0.y * v0.y + v0.z * v0.z + v0.w * v0.w
                + v1.x * v1.x + v1.y * v1.y + v1.z * v1.z + v1.w * v1.w
                + v2.x * v2.x + v2.y * v2.y + v2.z * v2.z + v2.w * v2.w
                + v3.x * v3.x + v3.y * v3.y + v3.z * v3.z + v3.w * v3.w;
        s += __shfl_xor(s, 1, 64);
        s += __shfl_xor(s, 2, 64);
        s += __shfl_xor(s, 4, 64);
        s += __shfl_xor(s, 8, 64);
        const float iv = 1.0f / sqrtf(s);
        const int ks2 = seg >> 2;
        const int half = (seg >> 1) & 1;
        const int ga = (seg * 2) & 3;
        const int gb = (seg * 2 + 1) & 3;
        unsigned char* base = negT + (size_t)bid * 4096;
        uint2 pa, pb;
        pa.x = pk4(v0.x * iv, v0.y * iv, v0.z * iv, v0.w * iv);
        pa.y = pk4(v1.x * iv, v1.y * iv, v1.z * iv, v1.w * iv);
        pb.x = pk4(v2.x * iv, v2.y * iv, v2.z * iv, v2.w * iv);
        pb.y = pk4(v3.x * iv, v3.y * iv, v3.z * iv, v3.w * iv);
        *reinterpret_cast<uint2*>(base + (((ks2 * 4 + ga) * 16 + col) * 16) + half * 8) = pa;
        *reinterpret_cast<uint2*>(base + (((ks2 * 4 + gb) * 16 + col) * 16) + half * 8) = pb;
        return;
    }
    if (bid < 2560) {   // ---- kanchor: rows (bid-2048)*4 .. +3 ----
        const int r = (bid - 2048) * 4 + (tid >> 6);
        const int lane = tid & 63;
        const int b = r >> 7;
        const int n = r & 127;
        const int t = mask_index[n];
        const size_t base = ((size_t)b * TT + t) * TD;
        float4 a = *reinterpret_cast<const float4*>(ctx + base + lane * 4);
        float4 p = *reinterpret_cast<const float4*>(tgt + base + lane * 4);
        float sa = a.x * a.x + a.y * a.y + a.z * a.z + a.w * a.w;
        float sp = p.x * p.x + p.y * p.y + p.z * p.z + p.w * p.w;
        float dp = a.x * p.x + a.y * p.y + a.z * p.z + a.w * p.w;
        for (int off = 32; off > 0; off >>= 1) {
            sa += __shfl_down(sa, off, 64);
            sp += __shfl_down(sp, off, 64);
            dp += __shfl_down(dp, off, 64);
        }
        sa = __shfl(sa, 0, 64);
        sp = __shfl(sp, 0, 64);
        dp = __shfl(dp, 0, 64);
        const float an = sqrtf(sa);
        const float inva = 1.0f / an;
        if (lane == 0) {
            float cp = dp / (an * sqrtf(sp));
            cp = fminf(1.f, fmaxf(-1.f, cp));
            acosP[r] = acosf(cp) * 10.0f;
            phoneA[r] = phone[b * TT + t];
        }
        // dims d = lane*4 .. +3: ks2=lane>>4, half=(lane>>3)&1, g=(lane>>1)&3, e=(lane&1)*4
        const unsigned u = pk4(a.x * inva, a.y * inva, a.z * inva, a.w * inva);
        unsigned char* ab = ancT + (size_t)(r >> 4) * 4096;
        *reinterpret_cast<unsigned*>(
            ab + ((((lane >> 4) * 4 + ((lane >> 1) & 3)) * 16 + (r & 15)) * 16)
               + ((lane >> 3) & 1) * 8 + (lane & 1) * 4) = u;
        return;
    }
    if (bid < 2560 + GH) {   // ---- ghist partial slice ----
        __shared__ unsigned h[128];
        const int s = bid - 2560;
        if (tid < 128) h[tid] = 0u;
        __syncthreads();
        const int base = s * (BT / GH);
        for (int i = tid; i < BT / GH; i += 256)
            atomicAdd(&h[phone[base + i] & 127], 1u);
        __syncthreads();
        if (tid < 128) ghp[s * 128 + tid] = h[tid];
        return;
    }
    {   // ---- zero cnt/flag ----
        const int i = (bid - 2592) * 256 + tid;
        if (i < BN) { cnt[i] = 0; flagA[i] = 0; }
    }
}

// ---------------------------------------------------------------------------
// Barrier-free GEMM pass (fp8 operands): 128 rows x 512 cols per block,
// 8 waves (4 row-groups x 2 col-groups), launch_bounds(512,4) = 2 blocks/CU
// with register-resident operands. Single change vs R18: unroll 4 on the
// column loop — up to 4 iterations' load chains (16+4 loads) in flight,
// using the ~80-VGPR headroom (R18: VGPR 44 of 128 budget).
// ---------------------------------------------------------------------------
__global__ __launch_bounds__(512, 4) void kpass(const long2v* __restrict__ ancTL,
                                                const long2v* __restrict__ negTL,
                                                const int* __restrict__ phoneT,
                                                const int* __restrict__ phoneA,
                                                float* __restrict__ list,
                                                int* __restrict__ cnt,
                                                int* __restrict__ flag) {
    __shared__ float candV[LCAP];
    __shared__ int candR[LCAP];
    __shared__ int s_nc;
    const int tid = threadIdx.x;
    const int w = tid >> 6;
    const int lane = tid & 63;
    const int g = lane >> 4;
    const int c = lane & 15;
    const int wr = w >> 1;              // row-group 0..3
    const int wc = w & 1;               // col-group 0..1
    // bijective XCD swizzle (1024 % 8 == 0): co-XCD blocks share ct slices
    const int logical = (blockIdx.x & 7) * 128 + (blockIdx.x >> 3);
    const int ct = logical >> 4;        // 0..63
    const int rt = logical & 15;        // 0..15
    const int row0 = rt * BROWS;
    const int colbase = ct * SLICE;

    if (tid == 0) s_nc = 0;

    long2v afp[2][4];
#pragma unroll
    for (int mt = 0; mt < 2; ++mt) {
        const int tile = rt * 8 + wr * 2 + mt;
#pragma unroll
        for (int ks2 = 0; ks2 < 4; ++ks2)
            afp[mt][ks2] = ancTL[tile * 256 + ks2 * 64 + lane];
    }
    int phA_r[2][4];
#pragma unroll
    for (int mt = 0; mt < 2; ++mt)
#pragma unroll
        for (int j = 0; j < 4; ++j)
            phA_r[mt][j] = phoneA[row0 + wr * 32 + mt * 16 + g * 4 + j];
    __syncthreads();   // s_nc visible

#pragma unroll 4
    for (int it = 0; it < NITER; ++it) {
        const int cb = colbase + it * 32 + wc * 16;   // wave's 16 cols
        const int cblk = cb >> 4;
        long2v bq[4];
#pragma unroll
        for (int ks2 = 0; ks2 < 4; ++ks2)
            bq[ks2] = negTL[cblk * 256 + ks2 * 64 + lane];
        const int ph = phoneT[cb + c];
        float4v acc0 = (float4v){0.f, 0.f, 0.f, 0.f};
        float4v acc1 = (float4v){0.f, 0.f, 0.f, 0.f};
        __builtin_amdgcn_s_setprio(1);
#pragma unroll
        for (int ks2 = 0; ks2 < 4; ++ks2) {
            acc0 = __builtin_amdgcn_mfma_f32_16x16x32_fp8_fp8(afp[0][ks2].x, bq[ks2].x, acc0, 0, 0, 0);
            acc1 = __builtin_amdgcn_mfma_f32_16x16x32_fp8_fp8(afp[1][ks2].x, bq[ks2].x, acc1, 0, 0, 0);
            acc0 = __builtin_amdgcn_mfma_f32_16x16x32_fp8_fp8(afp[0][ks2].y, bq[ks2].y, acc0, 0, 0, 0);
            acc1 = __builtin_amdgcn_mfma_f32_16x16x32_fp8_fp8(afp[1][ks2].y, bq[ks2].y, acc1, 0, 0, 0);
        }
        __builtin_amdgcn_s_setprio(0);
#pragma unroll
        for (int j = 0; j < 4; ++j) {
            float v0 = acc0[j];
            if (v0 < THETA && ph != phA_r[0][j]) {
                int k = atomicAdd(&s_nc, 1);
                if (k < LCAP) {
                    candV[k] = fmaxf(-1.f, v0);
                    candR[k] = row0 + wr * 32 + g * 4 + j;
                }
            }
            float v1 = acc1[j];
            if (v1 < THETA && ph != phA_r[1][j]) {
                int k = atomicAdd(&s_nc, 1);
                if (k < LCAP) {
                    candV[k] = fmaxf(-1.f, v1);
                    candR[k] = row0 + wr * 32 + 16 + g * 4 + j;
                }
            }
        }
    }

    __syncthreads();
    const int nc = s_nc;
    if (nc > LCAP) {   // astronomically unlikely: flag block rows for fallback
        for (int i = tid; i < BROWS; i += 512) flag[row0 + i] = 1;
    } else {
        for (int i = tid; i < nc; i += 512) {
            const int r = candR[i];
            int idx = atomicAdd(&cnt[r], 1);
            if (idx < CAP) list[(size_t)r * CAP + idx] = candV[i];
        }
    }
}

// ---------------------------------------------------------------------------
// per-row final: exact bottom-kp selection among candidates + exp/acos sum.
// ---------------------------------------------------------------------------
__global__ __launch_bounds__(64) void kfinal(const float* __restrict__ list,
                                             const int* __restrict__ cnt,
                                             const int* __restrict__ phoneA,
                                             const unsigned* __restrict__ ghp,
                                             const float* __restrict__ acosP,
                                             float* __restrict__ logits,
                                             int* __restrict__ flag) {
    __shared__ float sl[CAP];
    __shared__ unsigned subh[256];
    __shared__ float l2[128];
    __shared__ int s_b, s_cum, s_l2c;
    const int row = blockIdx.x;
    const int lane = threadIdx.x;
    const int mp = phoneA[row] & 127;
    int un = BT;
    for (int s = 0; s < GH; ++s) un -= (int)ghp[s * 128 + mp];
    const int kp = un < KTOP ? un : KTOP;
    const int c = cnt[row];
    if (kp <= 0) { if (lane == 0) logits[row] = acosP[row]; return; }
    if (c < kp || c > CAP) { if (lane == 0) flag[row] = 1; return; }

    for (int i = lane; i < c; i += 64) sl[i] = list[(size_t)row * CAP + i];
    for (int i = lane; i < 256; i += 64) subh[i] = 0u;
    if (lane == 0) s_l2c = 0;
    __syncthreads();

    for (int i = lane; i < c; i += 64) {
        int sb = (int)((sl[i] + 1.0f) * FSCALE);
        sb = sb < 0 ? 0 : (sb > 255 ? 255 : sb);
        atomicAdd(&subh[sb], 1u);
    }
    __syncthreads();
    if (lane == 0) {
        unsigned cum = 0;
        int b = 0;
        for (; b < 256; ++b) {
            if (cum + subh[b] >= (unsigned)kp) break;
            cum += subh[b];
        }
        s_b = b > 255 ? 255 : b;
        s_cum = (int)cum;
    }
    __syncthreads();
    const int bs = s_b, cum = s_cum;

    float ls = 0.f;
    for (int i = lane; i < c; i += 64) {
        float v = sl[i];
        int sb = (int)((v + 1.0f) * FSCALE);
        sb = sb < 0 ? 0 : (sb > 255 ? 255 : sb);
        if (sb < bs) {
            ls += expf(acosf(fminf(1.f, fmaxf(-1.f, v))) * 10.0f);
        } else if (sb == bs) {
            int k = atomicAdd(&s_l2c, 1);
            if (k < 128) l2[k] = v;
        }
    }
#pragma unroll
    for (int off = 1; off < 64; off <<= 1) ls += __shfl_xor(ls, off, 64);
    __syncthreads();
    const int n2 = s_l2c;
    if (n2 > 128) { if (lane == 0) flag[row] = 1; return; }

    float den = ls;
    int rem = kp - cum;
    if (rem > n2) rem = n2;
    float v0 = lane < n2 ? l2[lane] : 1e30f;
    float v1 = lane + 64 < n2 ? l2[lane + 64] : 1e30f;
    for (int it = 0; it < rem; ++it) {
        float mv = fminf(v0, v1);
        int mi = (v1 < v0) ? lane + 64 : lane;
#pragma unroll
        for (int off = 1; off < 64; off <<= 1) {
            float ov = __shfl_xor(mv, off, 64);
            int oi = __shfl_xor(mi, off, 64);
            if (ov < mv || (ov == mv && oi < mi)) { mv = ov; mi = oi; }
        }
        den += expf(acosf(fminf(1.f, fmaxf(-1.f, mv))) * 10.0f);
        if (mi == lane) v0 = 1e30f;
        if (mi == lane + 64) v1 = 1e30f;
    }
    if (lane == 0) logits[row] = acosP[row] - logf(den);
}

// ---------------------------------------------------------------------------
// exact fallback for flagged rows (cold path, never expected).
// ---------------------------------------------------------------------------
__global__ __launch_bounds__(256) void kfallback(const float* __restrict__ ctx,
                                                 const float* __restrict__ tgt,
                                                 const int* __restrict__ mask_index,
                                                 const int* __restrict__ phone,
                                                 const int* __restrict__ flag,
                                                 const unsigned* __restrict__ ghp,
                                                 const float* __restrict__ acosP,
                                                 float* __restrict__ logits) {
    const int row = blockIdx.x;
    if (!flag[row]) return;
    __shared__ float anc[TD];
    __shared__ float redf[256];
    __shared__ int redi[256];
    __shared__ unsigned hist[2048];
    __shared__ float lst[512];
    __shared__ int s_b, s_cum, s_lc;
    const int tid = threadIdx.x;
    const int b = row >> 7;
    const int t = mask_index[row & 127];
    const int mp = phone[b * TT + t];

    {
        float x = ctx[((size_t)b * TT + t) * TD + tid];
        redf[tid] = x * x;
        anc[tid] = x;
        __syncthreads();
        for (int s = 128; s > 0; s >>= 1) {
            if (tid < s) redf[tid] += redf[tid + s];
            __syncthreads();
        }
        float inv = 1.0f / sqrtf(redf[0]);
        __syncthreads();
        anc[tid] *= inv;
    }
    for (int i = tid; i < 2048; i += 256) hist[i] = 0u;
    if (tid == 0) s_lc = 0;
    __syncthreads();

    int un = BT;
    for (int s = 0; s < GH; ++s) un -= (int)ghp[s * 128 + (mp & 127)];
    const int kp = un < KTOP ? un : KTOP;
    if (kp <= 0) { if (tid == 0) logits[row] = acosP[row]; return; }

    for (int col = tid; col < BT; col += 256) {
        if (phone[col] == mp) continue;
        const float* nr = tgt + (size_t)col * TD;
        float dot = 0.f, sq = 0.f;
        for (int d = 0; d < TD; d += 4) {
            float4 v = *reinterpret_cast<const float4*>(nr + d);
            dot += anc[d] * v.x + anc[d + 1] * v.y + anc[d + 2] * v.z + anc[d + 3] * v.w;
            sq += v.x * v.x + v.y * v.y + v.z * v.z + v.w * v.w;
        }
        float cv = fminf(1.f, fmaxf(-1.f, dot / sqrtf(sq)));
        int bb = (int)((cv + 1.0f) * 1024.0f);
        bb = bb > 2047 ? 2047 : bb;
        atomicAdd(&hist[bb], 1u);
    }
    __syncthreads();
    if (tid == 0) {
        unsigned cum = 0;
        int bb = 0;
        for (; bb < 2048; ++bb) {
            if (cum + hist[bb] >= (unsigned)kp) break;
            cum += hist[bb];
        }
        s_b = bb > 2047 ? 2047 : bb;
        s_cum = (int)cum;
    }
    __syncthreads();
    const int bs = s_b;

    float ls = 0.f;
    for (int col = tid; col < BT; col += 256) {
        if (phone[col] == mp) continue;
        const float* nr = tgt + (size_t)col * TD;
        float dot = 0.f, sq = 0.f;
        for (int d = 0; d < TD; d += 4) {
            float4 v = *reinterpret_cast<const float4*>(nr + d);
            dot += anc[d] * v.x + anc[d + 1] * v.y + anc[d + 2] * v.z + anc[d + 3] * v.w;
            sq += v.x * v.x + v.y * v.y + v.z * v.z + v.w * v.w;
        }
        float cv = fminf(1.f, fmaxf(-1.f, dot / sqrtf(sq)));
        int bb = (int)((cv + 1.0f) * 1024.0f);
        bb = bb > 2047 ? 2047 : bb;
        if (bb < bs) {
            ls += expf(acosf(cv) * 10.0f);
        } else if (bb == bs) {
            int k = atomicAdd(&s_lc, 1);
            if (k < 512) lst[k] = cv;
        }
    }
    redf[tid] = ls;
    __syncthreads();
    for (int s = 128; s > 0; s >>= 1) {
        if (tid < s) redf[tid] += redf[tid + s];
        __syncthreads();
    }
    float den = redf[0];
    __syncthreads();

    int lc = s_lc < 512 ? s_lc : 512;
    int rem = kp - s_cum;
    if (rem > lc) rem = lc;
    for (int it = 0; it < rem; ++it) {
        float mv = 1e30f;
        int mi = -1;
        for (int i = tid; i < lc; i += 256) {
            if (lst[i] < mv) { mv = lst[i]; mi = i; }
        }
        redf[tid] = mv;
        redi[tid] = mi;
        __syncthreads();
        for (int s = 128; s > 0; s >>= 1) {
            if (tid < s && (redf[tid + s] < redf[tid] ||
                            (redf[tid + s] == redf[tid] && redi[tid + s] >= 0 &&
                             (redi[tid] < 0 || redi[tid + s] < redi[tid])))) {
                redf[tid] = redf[tid + s];
                redi[tid] = redi[tid + s];
            }
            __syncthreads();
        }
        if (tid == 0) {
            den += expf(acosf(fminf(1.f, fmaxf(-1.f, redf[0]))) * 10.0f);
            if (redi[0] >= 0) lst[redi[0]] = 1e30f;
            redf[0] = den;
        }
        __syncthreads();
        den = redf[0];
        __syncthreads();
    }
    if (tid == 0) logits[row] = acosP[row] - logf(den);
}

__global__ __launch_bounds__(256) void kloss(const float* __restrict__ logits,
                                             float* __restrict__ out) {
    __shared__ float red[256];
    int tid = threadIdx.x;
    float s = 0.f;
    for (int i = tid; i < BN; i += 256) s += logits[i];
    red[tid] = s;
    __syncthreads();
    for (int st = 128; st > 0; st >>= 1) {
        if (tid < st) red[tid] += red[tid + st];
        __syncthreads();
    }
    if (tid == 0) out[0] = -red[0] / (float)BN;
}

extern "C" void kernel_launch(void* const* d_in, const int* in_sizes, int n_in,
                              void* d_out, int out_size, void* d_ws, size_t ws_size,
                              hipStream_t stream) {
    (void)in_sizes; (void)n_in; (void)out_size; (void)ws_size;
    const float* ctx   = (const float*)d_in[0];
    const float* tgt   = (const float*)d_in[1];
    const int*   mask  = (const int*)d_in[2];
    const int*   phone = (const int*)d_in[3];
    float* out = (float*)d_out;

    char* p = (char*)d_ws;
    unsigned char* negT = (unsigned char*)p;              p += (size_t)BT * TD;       // 8 MB
    unsigned char* ancT = (unsigned char*)p;              p += (size_t)BN * TD;       // 512 KB
    float* acosP  = (float*)p;                            p += (size_t)BN * 4;
    int*   phoneA = (int*)p;                              p += (size_t)BN * 4;
    int*   cntA   = (int*)p;                              p += (size_t)BN * 4;
    int*   flagA  = (int*)p;                              p += (size_t)BN * 4;
    unsigned* ghp = (unsigned*)p;                         p += (size_t)GH * 128 * 4;
    float* listA  = (float*)p;                            p += (size_t)BN * CAP * 4;  // 8 MB
    float* logits = (float*)p;                            p += (size_t)BN * 4;

    kinit<<<2600, 256, 0, stream>>>(ctx, tgt, mask, phone, negT, ancT,
                                    acosP, phoneA, ghp, cntA, flagA);
    kpass<<<1024, 512, 0, stream>>>((const long2v*)ancT, (const long2v*)negT,
                                    phone, phoneA, listA, cntA, flagA);
    kfinal<<<BN, 64, 0, stream>>>(listA, cntA, phoneA, ghp, acosP, logits, flagA);
    kfallback<<<BN, 256, 0, stream>>>(ctx, tgt, mask, phone, flagA, ghp, acosP, logits);
    kloss<<<1, 256, 0, stream>>>(logits, out);
}